// Round 5
// baseline (245.217 us; speedup 1.0000x reference)
//
#include <hip/hip_runtime.h>
#include <hip/hip_bf16.h>

// HorizonTemporalSelfAttention: multi-scale deformable attention
// bs=2, nq=16384, E=256, NH=8, NL=4, NP=4, d=32, total tokens=21760
//
// R5: GEMM reads query exactly once (M=128 x N=384 block tile, 8 waves,
//     B frags direct from L2-resident f16 W); sampler gets XCD-affinity
//     swizzle (blocks of head h -> XCD h, value slice L2-resident).

typedef __attribute__((ext_vector_type(4))) float    float4v;
typedef __attribute__((ext_vector_type(8))) _Float16 half8;
typedef __attribute__((ext_vector_type(4))) _Float16 half4;
typedef __attribute__((ext_vector_type(2))) _Float16 half2v;

#define NQ    16384
#define NTOK  21760
#define NLOG  384

#define N_V4  2785280   // value f32 in float4 units

union H8 { half8 v; half2v p[4]; };

// ---------------- K1: convert value + Wcat f32 -> f16 ----------------
__global__ __launch_bounds__(256) void convert_kernel(
    const float* __restrict__ val,
    const float* __restrict__ Woff, const float* __restrict__ Wattn,
    _Float16* __restrict__ vh, _Float16* __restrict__ wh) {
  int i = blockIdx.x * 256 + threadIdx.x;
  float4v v;
  half4* dst;
  if (i < N_V4) {
    v = ((const float4v*)val)[i];
    dst = ((half4*)vh) + i;
  } else {
    int j = i - N_V4;                    // [0, 24576)
    int n = j >> 6;                      // Wcat row 0..383
    int k4 = j & 63;
    const float* src = (n < 256) ? (Woff + (size_t)n * 256)
                                 : (Wattn + (size_t)(n - 256) * 256);
    v = *(const float4v*)(src + k4 * 4);
    dst = ((half4*)wh) + j;
  }
  half4 o;
  o[0] = (_Float16)v[0]; o[1] = (_Float16)v[1];
  o[2] = (_Float16)v[2]; o[3] = (_Float16)v[3];
  *dst = o;
}

// ---------------- K2: MFMA GEMM, M=128 x N=384(all), K=256 ----------------
// grid (256): 512 threads = 8 waves in 2(m) x 4(n); wave tile 64 x 96.
// A staged f32->f16 to LDS in two K=128 chunks; B frags direct from wh (L2).
#define ALD 136   // 128 k-halves + 8 pad
__global__ __launch_bounds__(512, 2) void gemm_kernel(
    const float* __restrict__ qf, const _Float16* __restrict__ wh,
    const float* __restrict__ boff, const float* __restrict__ battn,
    _Float16* __restrict__ lh) {
  __shared__ _Float16 As[128 * ALD];

  const int tid  = threadIdx.x;
  const int lane = tid & 63;
  const int wv   = tid >> 6;           // 0..7
  const int wm   = wv >> 2, wn = wv & 3;
  const int quad = lane >> 4;
  const int r    = lane & 15;
  const int blockM = blockIdx.x * 128;

  float4v acc[4][6];
#pragma unroll
  for (int i = 0; i < 4; ++i)
#pragma unroll
    for (int j = 0; j < 6; ++j) acc[i][j] = (float4v){0.f, 0.f, 0.f, 0.f};

  for (int kc = 0; kc < 2; ++kc) {
    const int k0 = kc * 128;
    if (kc) __syncthreads();
    // stage A chunk: 128 rows x 32 float4 = 4096 float4 over 512 threads
#pragma unroll
    for (int it = 0; it < 8; ++it) {
      int idx = it * 512 + tid;
      int row = idx >> 5, k4 = idx & 31;
      float4v v = *(const float4v*)(qf + (size_t)(blockM + row) * 256 + k0 + k4 * 4);
      half4 o;
      o[0] = (_Float16)v[0]; o[1] = (_Float16)v[1];
      o[2] = (_Float16)v[2]; o[3] = (_Float16)v[3];
      *(half4*)&As[row * ALD + k4 * 4] = o;
    }
    __syncthreads();

#pragma unroll
    for (int kt = 0; kt < 4; ++kt) {
      const int ko = kt * 32 + quad * 8;
      half8 af[4], bf[6];
#pragma unroll
      for (int mi = 0; mi < 4; ++mi)
        af[mi] = *(const half8*)&As[(wm * 64 + mi * 16 + r) * ALD + ko];
#pragma unroll
      for (int ni = 0; ni < 6; ++ni)
        bf[ni] = *(const half8*)(wh + (size_t)(wn * 96 + ni * 16 + r) * 256 + k0 + ko);
#pragma unroll
      for (int mi = 0; mi < 4; ++mi)
#pragma unroll
        for (int ni = 0; ni < 6; ++ni)
          acc[mi][ni] = __builtin_amdgcn_mfma_f32_16x16x32_f16(af[mi], bf[ni], acc[mi][ni], 0, 0, 0);
    }
  }

#pragma unroll
  for (int mi = 0; mi < 4; ++mi) {
    const int mb = blockM + wm * 64 + mi * 16 + quad * 4;
#pragma unroll
    for (int ni = 0; ni < 6; ++ni) {
      const int n = wn * 96 + ni * 16 + r;
      const float bias = (n < 256) ? boff[n] : battn[n - 256];
#pragma unroll
      for (int reg = 0; reg < 4; ++reg)
        lh[(size_t)(mb + reg) * NLOG + n] = (_Float16)(acc[mi][ni][reg] + bias);
    }
  }
}

// ---------------- K3: sampling (packed f16 blend, XCD-affine) ----------------
// grid (16, 256): x = hb = h + 8*b  (linear%8 == h -> per-head XCD L2 locality),
//                 y = q-tile of 64. block 256; c4 = tid&3 (8ch), qi = tid>>2.
__global__ __launch_bounds__(256) void sample_kernel(
    const _Float16* __restrict__ vh, const float* __restrict__ refp,
    const _Float16* __restrict__ lh, float* __restrict__ out) {
  const int hb = blockIdx.x;
  const int h = hb & 7, b = hb >> 3;
  const int qt = blockIdx.y;
  const int tid = threadIdx.x;
  const int c4 = tid & 3;
  const int qi = tid >> 2;
  const int q  = qt * 64 + qi;
  const size_t bq = (size_t)b * NQ + q;
  const _Float16* lg = lh + bq * NLOG;

  // offsets: 32 halves at h*32, layout l*8 + p*2 + xy
  float offf[32];
#pragma unroll
  for (int i = 0; i < 4; ++i) {
    half8 oh = *(const half8*)(lg + h * 32 + i * 8);
#pragma unroll
    for (int j = 0; j < 8; ++j) offf[i * 8 + j] = (float)oh[j];
  }
  // attn logits: 16 halves at 256 + h*16 -> softmax (f32)
  float al[16];
#pragma unroll
  for (int i = 0; i < 2; ++i) {
    half8 ah = *(const half8*)(lg + 256 + h * 16 + i * 8);
#pragma unroll
    for (int j = 0; j < 8; ++j) al[i * 8 + j] = (float)ah[j];
  }
  float mx = -1e30f;
#pragma unroll
  for (int i = 0; i < 16; ++i) mx = fmaxf(mx, al[i]);
  float ssum = 0.f;
#pragma unroll
  for (int i = 0; i < 16; ++i) {
    float e = __expf(al[i] - mx);
    al[i] = e;
    ssum += e;
  }
  const float inv = 1.0f / ssum;

  float4v rp0 = *(const float4v*)(refp + bq * 8);
  float4v rp1 = *(const float4v*)(refp + bq * 8 + 4);
  const float rpx[4] = {rp0[0], rp0[2], rp1[0], rp1[2]};
  const float rpy[4] = {rp0[1], rp0[3], rp1[1], rp1[3]};

  const _Float16* vb = vh + (size_t)b * NTOK * 256 + h * 32 + c4 * 8;
  float4v acc0 = (float4v){0.f, 0.f, 0.f, 0.f};
  float4v acc1 = (float4v){0.f, 0.f, 0.f, 0.f};

  const int base[4] = {0, 16384, 20480, 21504};

#pragma unroll
  for (int l = 0; l < 4; ++l) {
    const int   W  = 128 >> l;
    const float fW = (float)W;
    const _Float16* vlev = vb + (size_t)base[l] * 256;
    half2v accl[4];
#pragma unroll
    for (int j = 0; j < 4; ++j) accl[j] = (half2v){(_Float16)0, (_Float16)0};
#pragma unroll
    for (int p = 0; p < 4; ++p) {
      const float a  = al[l * 4 + p] * inv;
      const float ox = offf[l * 8 + p * 2];
      const float oy = offf[l * 8 + p * 2 + 1];
      // (ref + off/shape)*2-1 through grid_sample == ref*W + off - 0.5
      const float x = rpx[p] * fW + ox - 0.5f;
      const float y = rpy[p] * fW + oy - 0.5f;
      const float xf = floorf(x), yf = floorf(y);
      const float fx = x - xf, fy = y - yf;
      const int ix = (int)xf, iy = (int)yf;
      const int ix0 = min(max(ix, 0), W - 1);
      const int ix1 = min(max(ix + 1, 0), W - 1);
      const int iy0 = min(max(iy, 0), W - 1);
      const int iy1 = min(max(iy + 1, 0), W - 1);
      const float wx0 = ((unsigned)ix       < (unsigned)W) ? 1.f - fx : 0.f;
      const float wx1 = ((unsigned)(ix + 1) < (unsigned)W) ? fx       : 0.f;
      const float wy0 = ((unsigned)iy       < (unsigned)W) ? 1.f - fy : 0.f;
      const float wy1 = ((unsigned)(iy + 1) < (unsigned)W) ? fy       : 0.f;
      const _Float16 w00 = (_Float16)(a * wx0 * wy0);
      const _Float16 w01 = (_Float16)(a * wx1 * wy0);
      const _Float16 w10 = (_Float16)(a * wx0 * wy1);
      const _Float16 w11 = (_Float16)(a * wx1 * wy1);
      const half2v h00 = (half2v){w00, w00};
      const half2v h01 = (half2v){w01, w01};
      const half2v h10 = (half2v){w10, w10};
      const half2v h11 = (half2v){w11, w11};
      const _Float16* r0 = vlev + (size_t)(iy0 * W) * 256;
      const _Float16* r1 = vlev + (size_t)(iy1 * W) * 256;
      H8 t00, t01, t10, t11;
      t00.v = *(const half8*)(r0 + ix0 * 256);
      t01.v = *(const half8*)(r0 + ix1 * 256);
      t10.v = *(const half8*)(r1 + ix0 * 256);
      t11.v = *(const half8*)(r1 + ix1 * 256);
#pragma unroll
      for (int j = 0; j < 4; ++j) {
        accl[j] += h00 * t00.p[j] + h01 * t01.p[j]
                 + h10 * t10.p[j] + h11 * t11.p[j];
      }
    }
    // flush level accumulator to f32
    acc0[0] += (float)accl[0][0]; acc0[1] += (float)accl[0][1];
    acc0[2] += (float)accl[1][0]; acc0[3] += (float)accl[1][1];
    acc1[0] += (float)accl[2][0]; acc1[1] += (float)accl[2][1];
    acc1[2] += (float)accl[3][0]; acc1[3] += (float)accl[3][1];
  }

  // LDS transpose -> coalesced out[b][h*32+c][q]
  __shared__ float sm[32][65];
#pragma unroll
  for (int j = 0; j < 4; ++j) {
    sm[c4 * 8 + j][qi]     = acc0[j];
    sm[c4 * 8 + 4 + j][qi] = acc1[j];
  }
  __syncthreads();
  const size_t obase = ((size_t)b * 256 + h * 32) * NQ + qt * 64;
#pragma unroll
  for (int i = 0; i < 8; ++i) {
    const int idx = i * 256 + tid;
    const int c = idx >> 6, qq = idx & 63;
    out[obase + (size_t)c * NQ + qq] = sm[c][qq];
  }
}

extern "C" void kernel_launch(void* const* d_in, const int* in_sizes, int n_in,
                              void* d_out, int out_size, void* d_ws, size_t ws_size,
                              hipStream_t stream) {
  const float* query = (const float*)d_in[0];
  const float* value = (const float*)d_in[1];
  const float* refp  = (const float*)d_in[2];
  const float* Woff  = (const float*)d_in[3];
  const float* boff  = (const float*)d_in[4];
  const float* Wattn = (const float*)d_in[5];
  const float* battn = (const float*)d_in[6];
  float* out = (float*)d_out;

  char* ws = (char*)d_ws;
  _Float16* vh = (_Float16*)ws;                    // 22,282,240 B
  _Float16* wh = (_Float16*)(ws + 22282240);       //    196,608 B
  _Float16* lh = (_Float16*)(ws + 22478848);       // 25,165,824 B

  convert_kernel<<<10976, 256, 0, stream>>>(value, Woff, Wattn, vh, wh);
  gemm_kernel<<<256, 512, 0, stream>>>(query, wh, boff, battn, lh);
  sample_kernel<<<dim3(16, 256), 256, 0, stream>>>(vh, refp, lh, out);
}

// Round 6
// 223.793 us; speedup vs baseline: 1.0957x; 1.0957x over previous
//
#include <hip/hip_runtime.h>
#include <hip/hip_bf16.h>

// HorizonTemporalSelfAttention: multi-scale deformable attention
// bs=2, nq=16384, E=256, NH=8, NL=4, NP=4, d=32, total tokens=21760
//
// R6: 2 dispatches. Kernel F fuses [GEMM (768 blocks, M=128xN=128, A/B staged
//     f32->f16, f16 logits out)] + [value f32->f16 convert (10880 blocks)]
//     as independent block ranges. Sampler reverted to R4 grid (qt,h,b) —
//     R5's hb-major swizzle thrashed L2 (FETCH 132->201 MB, 82->106 us).

typedef __attribute__((ext_vector_type(4))) float    float4v;
typedef __attribute__((ext_vector_type(8))) _Float16 half8;
typedef __attribute__((ext_vector_type(4))) _Float16 half4;
typedef __attribute__((ext_vector_type(2))) _Float16 half2v;

#define NQ    16384
#define NTOK  21760
#define NLOG  384

#define GEMM_BLOCKS 768   // 256 M-tiles x 3 N-tiles
#define CONV_BLOCKS 10880 // 2785280 float4 / 256

union H8 { half8 v; half2v p[4]; };

// ---------------- K-F: fused GEMM + value convert ----------------
#define LDSTR 88
__global__ __launch_bounds__(256) void fused_kernel(
    const float* __restrict__ qf,
    const float* __restrict__ Woff, const float* __restrict__ Wattn,
    const float* __restrict__ boff, const float* __restrict__ battn,
    const float* __restrict__ val,
    _Float16* __restrict__ lh, _Float16* __restrict__ vh) {
  const int tid = threadIdx.x;

  if (blockIdx.x >= GEMM_BLOCKS) {
    // ---- value convert: f32 -> f16, one float4 per thread ----
    int i = (blockIdx.x - GEMM_BLOCKS) * 256 + tid;
    float4v v = ((const float4v*)val)[i];
    half4 o;
    o[0] = (_Float16)v[0]; o[1] = (_Float16)v[1];
    o[2] = (_Float16)v[2]; o[3] = (_Float16)v[3];
    ((half4*)vh)[i] = o;
    return;
  }

  // ---- GEMM: logits[32768][384] = q @ Wcat^T + bias, f16 out ----
  __shared__ _Float16 As[128 * LDSTR];
  __shared__ _Float16 Bs[128 * LDSTR];

  const int lane = tid & 63;
  const int wv   = tid >> 6;
  const int wm   = wv >> 1, wn = wv & 1;
  const int quad = lane >> 4;
  const int r    = lane & 15;
  const int blockM = (blockIdx.x & 255) * 128;
  const int n0     = (blockIdx.x >> 8) * 128;

  float4v acc[4][4];
#pragma unroll
  for (int i = 0; i < 4; ++i)
#pragma unroll
    for (int j = 0; j < 4; ++j) acc[i][j] = (float4v){0.f, 0.f, 0.f, 0.f};

  for (int kc = 0; kc < 4; ++kc) {
    const int k0 = kc * 64;
    if (kc) __syncthreads();
    // A: 128 rows x 16 float4 k-cols, f32 -> f16
#pragma unroll
    for (int it = 0; it < 8; ++it) {
      int idx = it * 256 + tid;
      int row = idx >> 4, k4 = idx & 15;
      float4v v = *(const float4v*)(qf + (size_t)(blockM + row) * 256 + k0 + k4 * 4);
      half4 o;
      o[0] = (_Float16)v[0]; o[1] = (_Float16)v[1];
      o[2] = (_Float16)v[2]; o[3] = (_Float16)v[3];
      *(half4*)&As[row * LDSTR + k4 * 4] = o;
    }
    // B: 128 rows x 16 float4 k-cols from Wcat f32 (L2-resident, 394 KB)
#pragma unroll
    for (int it = 0; it < 8; ++it) {
      int idx = it * 256 + tid;
      int row = idx >> 4, k4 = idx & 15;
      int n = n0 + row;
      const float* src = (n < 256) ? (Woff + (size_t)n * 256)
                                   : (Wattn + (size_t)(n - 256) * 256);
      float4v v = *(const float4v*)(src + k0 + k4 * 4);
      half4 o;
      o[0] = (_Float16)v[0]; o[1] = (_Float16)v[1];
      o[2] = (_Float16)v[2]; o[3] = (_Float16)v[3];
      *(half4*)&Bs[row * LDSTR + k4 * 4] = o;
    }
    __syncthreads();

#pragma unroll
    for (int kf = 0; kf < 2; ++kf) {
      const int ko = kf * 32 + quad * 8;
      half8 af[4], bf[4];
#pragma unroll
      for (int mi = 0; mi < 4; ++mi)
        af[mi] = *(const half8*)&As[(wm * 64 + mi * 16 + r) * LDSTR + ko];
#pragma unroll
      for (int ni = 0; ni < 4; ++ni)
        bf[ni] = *(const half8*)&Bs[(wn * 64 + ni * 16 + r) * LDSTR + ko];
#pragma unroll
      for (int mi = 0; mi < 4; ++mi)
#pragma unroll
        for (int ni = 0; ni < 4; ++ni)
          acc[mi][ni] = __builtin_amdgcn_mfma_f32_16x16x32_f16(af[mi], bf[ni], acc[mi][ni], 0, 0, 0);
    }
  }

#pragma unroll
  for (int mi = 0; mi < 4; ++mi) {
    const int mb = blockM + wm * 64 + mi * 16 + quad * 4;
#pragma unroll
    for (int ni = 0; ni < 4; ++ni) {
      const int n = n0 + wn * 64 + ni * 16 + r;
      const float bias = (n < 256) ? boff[n] : battn[n - 256];
#pragma unroll
      for (int reg = 0; reg < 4; ++reg)
        lh[(size_t)(mb + reg) * NLOG + n] = (_Float16)(acc[mi][ni][reg] + bias);
    }
  }
}

// ---------------- K-S: sampling (packed f16 blend, R4 grid) ----------------
// grid (256, 8, 2) = (q-tile of 64, head, batch); block 256.
// thread: c4 = tid&3 -> channels c4*8..c4*8+7 (half8 taps); qi = tid>>2.
__global__ __launch_bounds__(256) void sample_kernel(
    const _Float16* __restrict__ vh, const float* __restrict__ refp,
    const _Float16* __restrict__ lh, float* __restrict__ out) {
  const int qt = blockIdx.x, h = blockIdx.y, b = blockIdx.z;
  const int tid = threadIdx.x;
  const int c4 = tid & 3;
  const int qi = tid >> 2;
  const int q  = qt * 64 + qi;
  const size_t bq = (size_t)b * NQ + q;
  const _Float16* lg = lh + bq * NLOG;

  // offsets: 32 halves at h*32, layout l*8 + p*2 + xy
  float offf[32];
#pragma unroll
  for (int i = 0; i < 4; ++i) {
    half8 oh = *(const half8*)(lg + h * 32 + i * 8);
#pragma unroll
    for (int j = 0; j < 8; ++j) offf[i * 8 + j] = (float)oh[j];
  }
  // attn logits: 16 halves at 256 + h*16 -> softmax (f32)
  float al[16];
#pragma unroll
  for (int i = 0; i < 2; ++i) {
    half8 ah = *(const half8*)(lg + 256 + h * 16 + i * 8);
#pragma unroll
    for (int j = 0; j < 8; ++j) al[i * 8 + j] = (float)ah[j];
  }
  float mx = -1e30f;
#pragma unroll
  for (int i = 0; i < 16; ++i) mx = fmaxf(mx, al[i]);
  float ssum = 0.f;
#pragma unroll
  for (int i = 0; i < 16; ++i) {
    float e = __expf(al[i] - mx);
    al[i] = e;
    ssum += e;
  }
  const float inv = 1.0f / ssum;

  float4v rp0 = *(const float4v*)(refp + bq * 8);
  float4v rp1 = *(const float4v*)(refp + bq * 8 + 4);
  const float rpx[4] = {rp0[0], rp0[2], rp1[0], rp1[2]};
  const float rpy[4] = {rp0[1], rp0[3], rp1[1], rp1[3]};

  const _Float16* vb = vh + (size_t)b * NTOK * 256 + h * 32 + c4 * 8;
  float4v acc0 = (float4v){0.f, 0.f, 0.f, 0.f};
  float4v acc1 = (float4v){0.f, 0.f, 0.f, 0.f};

  const int base[4] = {0, 16384, 20480, 21504};

#pragma unroll
  for (int l = 0; l < 4; ++l) {
    const int   W  = 128 >> l;
    const float fW = (float)W;
    const _Float16* vlev = vb + (size_t)base[l] * 256;
    half2v accl[4];
#pragma unroll
    for (int j = 0; j < 4; ++j) accl[j] = (half2v){(_Float16)0, (_Float16)0};
#pragma unroll
    for (int p = 0; p < 4; ++p) {
      const float a  = al[l * 4 + p] * inv;
      const float ox = offf[l * 8 + p * 2];
      const float oy = offf[l * 8 + p * 2 + 1];
      // (ref + off/shape)*2-1 through grid_sample == ref*W + off - 0.5
      const float x = rpx[p] * fW + ox - 0.5f;
      const float y = rpy[p] * fW + oy - 0.5f;
      const float xf = floorf(x), yf = floorf(y);
      const float fx = x - xf, fy = y - yf;
      const int ix = (int)xf, iy = (int)yf;
      const int ix0 = min(max(ix, 0), W - 1);
      const int ix1 = min(max(ix + 1, 0), W - 1);
      const int iy0 = min(max(iy, 0), W - 1);
      const int iy1 = min(max(iy + 1, 0), W - 1);
      const float wx0 = ((unsigned)ix       < (unsigned)W) ? 1.f - fx : 0.f;
      const float wx1 = ((unsigned)(ix + 1) < (unsigned)W) ? fx       : 0.f;
      const float wy0 = ((unsigned)iy       < (unsigned)W) ? 1.f - fy : 0.f;
      const float wy1 = ((unsigned)(iy + 1) < (unsigned)W) ? fy       : 0.f;
      const _Float16 w00 = (_Float16)(a * wx0 * wy0);
      const _Float16 w01 = (_Float16)(a * wx1 * wy0);
      const _Float16 w10 = (_Float16)(a * wx0 * wy1);
      const _Float16 w11 = (_Float16)(a * wx1 * wy1);
      const half2v h00 = (half2v){w00, w00};
      const half2v h01 = (half2v){w01, w01};
      const half2v h10 = (half2v){w10, w10};
      const half2v h11 = (half2v){w11, w11};
      const _Float16* r0 = vlev + (size_t)(iy0 * W) * 256;
      const _Float16* r1 = vlev + (size_t)(iy1 * W) * 256;
      H8 t00, t01, t10, t11;
      t00.v = *(const half8*)(r0 + ix0 * 256);
      t01.v = *(const half8*)(r0 + ix1 * 256);
      t10.v = *(const half8*)(r1 + ix0 * 256);
      t11.v = *(const half8*)(r1 + ix1 * 256);
#pragma unroll
      for (int j = 0; j < 4; ++j) {
        accl[j] += h00 * t00.p[j] + h01 * t01.p[j]
                 + h10 * t10.p[j] + h11 * t11.p[j];
      }
    }
    // flush level accumulator to f32
    acc0[0] += (float)accl[0][0]; acc0[1] += (float)accl[0][1];
    acc0[2] += (float)accl[1][0]; acc0[3] += (float)accl[1][1];
    acc1[0] += (float)accl[2][0]; acc1[1] += (float)accl[2][1];
    acc1[2] += (float)accl[3][0]; acc1[3] += (float)accl[3][1];
  }

  // LDS transpose -> coalesced out[b][h*32+c][q]
  __shared__ float sm[32][65];
#pragma unroll
  for (int j = 0; j < 4; ++j) {
    sm[c4 * 8 + j][qi]     = acc0[j];
    sm[c4 * 8 + 4 + j][qi] = acc1[j];
  }
  __syncthreads();
  const size_t obase = ((size_t)b * 256 + h * 32) * NQ + qt * 64;
#pragma unroll
  for (int i = 0; i < 8; ++i) {
    const int idx = i * 256 + tid;
    const int c = idx >> 6, qq = idx & 63;
    out[obase + (size_t)c * NQ + qq] = sm[c][qq];
  }
}

extern "C" void kernel_launch(void* const* d_in, const int* in_sizes, int n_in,
                              void* d_out, int out_size, void* d_ws, size_t ws_size,
                              hipStream_t stream) {
  const float* query = (const float*)d_in[0];
  const float* value = (const float*)d_in[1];
  const float* refp  = (const float*)d_in[2];
  const float* Woff  = (const float*)d_in[3];
  const float* boff  = (const float*)d_in[4];
  const float* Wattn = (const float*)d_in[5];
  const float* battn = (const float*)d_in[6];
  float* out = (float*)d_out;

  char* ws = (char*)d_ws;
  _Float16* vh = (_Float16*)ws;                    // 22,282,240 B
  _Float16* lh = (_Float16*)(ws + 22282240);       // 25,165,824 B

  fused_kernel<<<GEMM_BLOCKS + CONV_BLOCKS, 256, 0, stream>>>(
      query, Woff, Wattn, boff, battn, value, lh, vh);
  sample_kernel<<<dim3(256, 8, 2), 256, 0, stream>>>(vh, refp, lh, out);
}

// Round 7
// 217.839 us; speedup vs baseline: 1.1257x; 1.0273x over previous
//
#include <hip/hip_runtime.h>
#include <hip/hip_bf16.h>

// HorizonTemporalSelfAttention: multi-scale deformable attention
// bs=2, nq=16384, E=256, NH=8, NL=4, NP=4, d=32, total tokens=21760
//
// R7: logits stored as per-(b,h,q) 48-half records [32 off | 16 attn] so each
//     cacheline belongs to exactly one head (R6 row-major layout caused ~85 MB
//     of cross-head logit re-fetch in the sampler; FETCH 131 MB vs 48 MB ideal).
//     Fused [GEMM + value-convert] kernel from R6 kept; sampler grid (qt,h,b).

typedef __attribute__((ext_vector_type(4))) float    float4v;
typedef __attribute__((ext_vector_type(8))) _Float16 half8;
typedef __attribute__((ext_vector_type(4))) _Float16 half4;
typedef __attribute__((ext_vector_type(2))) _Float16 half2v;

#define NQ    16384
#define NTOK  21760
#define LREC  48          // halves per (b,h,q) logit record: 32 off + 16 attn

#define GEMM_BLOCKS 768   // 256 M-tiles x 3 N-tiles
#define CONV_BLOCKS 10880 // 2785280 float4 / 256

union H8 { half8 v; half2v p[4]; };

// ---------------- K-F: fused GEMM + value convert ----------------
#define LDSTR 88
__global__ __launch_bounds__(256) void fused_kernel(
    const float* __restrict__ qf,
    const float* __restrict__ Woff, const float* __restrict__ Wattn,
    const float* __restrict__ boff, const float* __restrict__ battn,
    const float* __restrict__ val,
    _Float16* __restrict__ lh, _Float16* __restrict__ vh) {
  const int tid = threadIdx.x;

  if (blockIdx.x >= GEMM_BLOCKS) {
    // ---- value convert: f32 -> f16, one float4 per thread ----
    int i = (blockIdx.x - GEMM_BLOCKS) * 256 + tid;
    float4v v = ((const float4v*)val)[i];
    half4 o;
    o[0] = (_Float16)v[0]; o[1] = (_Float16)v[1];
    o[2] = (_Float16)v[2]; o[3] = (_Float16)v[3];
    ((half4*)vh)[i] = o;
    return;
  }

  // ---- GEMM: logits = q @ Wcat^T + bias -> per-(b,h,q) records ----
  __shared__ _Float16 As[128 * LDSTR];
  __shared__ _Float16 Bs[128 * LDSTR];

  const int lane = tid & 63;
  const int wv   = tid >> 6;
  const int wm   = wv >> 1, wn = wv & 1;
  const int quad = lane >> 4;
  const int r    = lane & 15;
  const int blockM = (blockIdx.x & 255) * 128;
  const int n0     = (blockIdx.x >> 8) * 128;

  float4v acc[4][4];
#pragma unroll
  for (int i = 0; i < 4; ++i)
#pragma unroll
    for (int j = 0; j < 4; ++j) acc[i][j] = (float4v){0.f, 0.f, 0.f, 0.f};

  for (int kc = 0; kc < 4; ++kc) {
    const int k0 = kc * 64;
    if (kc) __syncthreads();
    // A: 128 rows x 16 float4 k-cols, f32 -> f16
#pragma unroll
    for (int it = 0; it < 8; ++it) {
      int idx = it * 256 + tid;
      int row = idx >> 4, k4 = idx & 15;
      float4v v = *(const float4v*)(qf + (size_t)(blockM + row) * 256 + k0 + k4 * 4);
      half4 o;
      o[0] = (_Float16)v[0]; o[1] = (_Float16)v[1];
      o[2] = (_Float16)v[2]; o[3] = (_Float16)v[3];
      *(half4*)&As[row * LDSTR + k4 * 4] = o;
    }
    // B: 128 rows x 16 float4 k-cols from Wcat f32 (L2-resident, 394 KB)
#pragma unroll
    for (int it = 0; it < 8; ++it) {
      int idx = it * 256 + tid;
      int row = idx >> 4, k4 = idx & 15;
      int n = n0 + row;
      const float* src = (n < 256) ? (Woff + (size_t)n * 256)
                                   : (Wattn + (size_t)(n - 256) * 256);
      float4v v = *(const float4v*)(src + k0 + k4 * 4);
      half4 o;
      o[0] = (_Float16)v[0]; o[1] = (_Float16)v[1];
      o[2] = (_Float16)v[2]; o[3] = (_Float16)v[3];
      *(half4*)&Bs[row * LDSTR + k4 * 4] = o;
    }
    __syncthreads();

#pragma unroll
    for (int kf = 0; kf < 2; ++kf) {
      const int ko = kf * 32 + quad * 8;
      half8 af[4], bf[4];
#pragma unroll
      for (int mi = 0; mi < 4; ++mi)
        af[mi] = *(const half8*)&As[(wm * 64 + mi * 16 + r) * LDSTR + ko];
#pragma unroll
      for (int ni = 0; ni < 4; ++ni)
        bf[ni] = *(const half8*)&Bs[(wn * 64 + ni * 16 + r) * LDSTR + ko];
#pragma unroll
      for (int mi = 0; mi < 4; ++mi)
#pragma unroll
        for (int ni = 0; ni < 4; ++ni)
          acc[mi][ni] = __builtin_amdgcn_mfma_f32_16x16x32_f16(af[mi], bf[ni], acc[mi][ni], 0, 0, 0);
    }
  }

  // epilogue: n -> (head, slot): n<256: h=n>>5, slot=n&31 (offsets)
  //                              n>=256: h=(n-256)>>4, slot=32+((n-256)&15)
#pragma unroll
  for (int mi = 0; mi < 4; ++mi) {
    const int mb = blockM + wm * 64 + mi * 16 + quad * 4;
#pragma unroll
    for (int ni = 0; ni < 4; ++ni) {
      const int n = n0 + wn * 64 + ni * 16 + r;
      const float bias = (n < 256) ? boff[n] : battn[n - 256];
      const int h    = (n < 256) ? (n >> 5) : ((n - 256) >> 4);
      const int slot = (n < 256) ? (n & 31) : (32 + ((n - 256) & 15));
#pragma unroll
      for (int reg = 0; reg < 4; ++reg) {
        const int bq = mb + reg;
        const int b = bq >> 14, q = bq & 16383;
        lh[((size_t)(b * 8 + h) * NQ + q) * LREC + slot] =
            (_Float16)(acc[mi][ni][reg] + bias);
      }
    }
  }
}

// ---------------- K-S: sampling (packed f16 blend, record logits) ----------------
// grid (256, 8, 2) = (q-tile of 64, head, batch); block 256.
// thread: c4 = tid&3 -> channels c4*8..c4*8+7 (half8 taps); qi = tid>>2.
__global__ __launch_bounds__(256) void sample_kernel(
    const _Float16* __restrict__ vh, const float* __restrict__ refp,
    const _Float16* __restrict__ lh, float* __restrict__ out) {
  const int qt = blockIdx.x, h = blockIdx.y, b = blockIdx.z;
  const int tid = threadIdx.x;
  const int c4 = tid & 3;
  const int qi = tid >> 2;
  const int q  = qt * 64 + qi;
  const size_t bq = (size_t)b * NQ + q;
  const _Float16* rec = lh + ((size_t)(b * 8 + h) * NQ + q) * LREC;

  // offsets: slots 0..31, layout l*8 + p*2 + xy
  float offf[32];
#pragma unroll
  for (int i = 0; i < 4; ++i) {
    half8 oh = *(const half8*)(rec + i * 8);
#pragma unroll
    for (int j = 0; j < 8; ++j) offf[i * 8 + j] = (float)oh[j];
  }
  // attn logits: slots 32..47 -> softmax (f32)
  float al[16];
#pragma unroll
  for (int i = 0; i < 2; ++i) {
    half8 ah = *(const half8*)(rec + 32 + i * 8);
#pragma unroll
    for (int j = 0; j < 8; ++j) al[i * 8 + j] = (float)ah[j];
  }
  float mx = -1e30f;
#pragma unroll
  for (int i = 0; i < 16; ++i) mx = fmaxf(mx, al[i]);
  float ssum = 0.f;
#pragma unroll
  for (int i = 0; i < 16; ++i) {
    float e = __expf(al[i] - mx);
    al[i] = e;
    ssum += e;
  }
  const float inv = 1.0f / ssum;

  float4v rp0 = *(const float4v*)(refp + bq * 8);
  float4v rp1 = *(const float4v*)(refp + bq * 8 + 4);
  const float rpx[4] = {rp0[0], rp0[2], rp1[0], rp1[2]};
  const float rpy[4] = {rp0[1], rp0[3], rp1[1], rp1[3]};

  const _Float16* vb = vh + (size_t)b * NTOK * 256 + h * 32 + c4 * 8;
  float4v acc0 = (float4v){0.f, 0.f, 0.f, 0.f};
  float4v acc1 = (float4v){0.f, 0.f, 0.f, 0.f};

  const int base[4] = {0, 16384, 20480, 21504};

#pragma unroll
  for (int l = 0; l < 4; ++l) {
    const int   W  = 128 >> l;
    const float fW = (float)W;
    const _Float16* vlev = vb + (size_t)base[l] * 256;
    half2v accl[4];
#pragma unroll
    for (int j = 0; j < 4; ++j) accl[j] = (half2v){(_Float16)0, (_Float16)0};
#pragma unroll
    for (int p = 0; p < 4; ++p) {
      const float a  = al[l * 4 + p] * inv;
      const float ox = offf[l * 8 + p * 2];
      const float oy = offf[l * 8 + p * 2 + 1];
      // (ref + off/shape)*2-1 through grid_sample == ref*W + off - 0.5
      const float x = rpx[p] * fW + ox - 0.5f;
      const float y = rpy[p] * fW + oy - 0.5f;
      const float xf = floorf(x), yf = floorf(y);
      const float fx = x - xf, fy = y - yf;
      const int ix = (int)xf, iy = (int)yf;
      const int ix0 = min(max(ix, 0), W - 1);
      const int ix1 = min(max(ix + 1, 0), W - 1);
      const int iy0 = min(max(iy, 0), W - 1);
      const int iy1 = min(max(iy + 1, 0), W - 1);
      const float wx0 = ((unsigned)ix       < (unsigned)W) ? 1.f - fx : 0.f;
      const float wx1 = ((unsigned)(ix + 1) < (unsigned)W) ? fx       : 0.f;
      const float wy0 = ((unsigned)iy       < (unsigned)W) ? 1.f - fy : 0.f;
      const float wy1 = ((unsigned)(iy + 1) < (unsigned)W) ? fy       : 0.f;
      const _Float16 w00 = (_Float16)(a * wx0 * wy0);
      const _Float16 w01 = (_Float16)(a * wx1 * wy0);
      const _Float16 w10 = (_Float16)(a * wx0 * wy1);
      const _Float16 w11 = (_Float16)(a * wx1 * wy1);
      const half2v h00 = (half2v){w00, w00};
      const half2v h01 = (half2v){w01, w01};
      const half2v h10 = (half2v){w10, w10};
      const half2v h11 = (half2v){w11, w11};
      const _Float16* r0 = vlev + (size_t)(iy0 * W) * 256;
      const _Float16* r1 = vlev + (size_t)(iy1 * W) * 256;
      H8 t00, t01, t10, t11;
      t00.v = *(const half8*)(r0 + ix0 * 256);
      t01.v = *(const half8*)(r0 + ix1 * 256);
      t10.v = *(const half8*)(r1 + ix0 * 256);
      t11.v = *(const half8*)(r1 + ix1 * 256);
#pragma unroll
      for (int j = 0; j < 4; ++j) {
        accl[j] += h00 * t00.p[j] + h01 * t01.p[j]
                 + h10 * t10.p[j] + h11 * t11.p[j];
      }
    }
    // flush level accumulator to f32
    acc0[0] += (float)accl[0][0]; acc0[1] += (float)accl[0][1];
    acc0[2] += (float)accl[1][0]; acc0[3] += (float)accl[1][1];
    acc1[0] += (float)accl[2][0]; acc1[1] += (float)accl[2][1];
    acc1[2] += (float)accl[3][0]; acc1[3] += (float)accl[3][1];
  }

  // LDS transpose -> coalesced out[b][h*32+c][q]
  __shared__ float sm[32][65];
#pragma unroll
  for (int j = 0; j < 4; ++j) {
    sm[c4 * 8 + j][qi]     = acc0[j];
    sm[c4 * 8 + 4 + j][qi] = acc1[j];
  }
  __syncthreads();
  const size_t obase = ((size_t)b * 256 + h * 32) * NQ + qt * 64;
#pragma unroll
  for (int i = 0; i < 8; ++i) {
    const int idx = i * 256 + tid;
    const int c = idx >> 6, qq = idx & 63;
    out[obase + (size_t)c * NQ + qq] = sm[c][qq];
  }
}

extern "C" void kernel_launch(void* const* d_in, const int* in_sizes, int n_in,
                              void* d_out, int out_size, void* d_ws, size_t ws_size,
                              hipStream_t stream) {
  const float* query = (const float*)d_in[0];
  const float* value = (const float*)d_in[1];
  const float* refp  = (const float*)d_in[2];
  const float* Woff  = (const float*)d_in[3];
  const float* boff  = (const float*)d_in[4];
  const float* Wattn = (const float*)d_in[5];
  const float* battn = (const float*)d_in[6];
  float* out = (float*)d_out;

  char* ws = (char*)d_ws;
  _Float16* vh = (_Float16*)ws;                    // 22,282,240 B
  _Float16* lh = (_Float16*)(ws + 22282240);       // 25,165,824 B

  fused_kernel<<<GEMM_BLOCKS + CONV_BLOCKS, 256, 0, stream>>>(
      query, Woff, Wattn, boff, battn, value, lh, vh);
  sample_kernel<<<dim3(256, 8, 2), 256, 0, stream>>>(vh, refp, lh, out);
}